// Round 11
// baseline (174.698 us; speedup 1.0000x reference)
//
#include <hip/hip_runtime.h>
#include <math.h>

// B=4096, T=64, C=64, H=8, D=8. fp32 in/out.
// d_ws fp16: WqkvT[n][c] (n: q 0-63 | k 64-127 | v 128-191), then W1T[j][c].
// Wk section PRE-SCALED by C^-0.5*log2(e) so softmax is exp2(S) directly.
// Main kernel: 256 thr (4 waves) per batch element, 6 blocks/CU (LDS 25600B).
// STRUCTURE = R9 (measured optimum 49.6us) with phase 0 DELETED: x B-frags
// are lane-indexed only (identical across waves), so each lane loads its
// 8 f32 directly from global (L1-served after first touch; every line fully
// consumed by the wave -> HBM FETCH unchanged) and cvt_pkrtz's in-register.
// Deletes the xs LDS staging, 2 barriers, and the region0 WAR hazard
// (region0 is now vth-only). R3-R8 lesson: phase-2 liveness EXTENSIONS
// (K/Q in regs, braid, mask-in-C, MFMA-denom) all spill-regressed; this
// round SHRINKS structure instead. R10 lesson: raw (unselected) qf/vfr
// loads add bank conflicts; R9's predicated forms restored. Tree-sum kept.
//  phase1: QKV^T = Wqkv^T x^T via 16x16x32_f16 (A=weights, B=x frags from
//          global). Packed C -> qh (Q), kh (K); V scalar -> vth. Barrier.
//  phase2: per wave, heads 2w,2w+1 with 16x16x16_f16 (K=16): A/B frags hold
//          k=4*quad+j == the S^T C-layout, so packed softmax output IS the
//          PV B-operand (no shuffle). S^T col tn: tm<=tn triangular MFMAs;
//          max-free softmax e=exp2(s) (scale pre-folded), causal cndmask on
//          diagonal, tree row-sum + shfl_xor(16,32); O^T = V^T P;
//          normalize by rcp; att -> qh. Barrier.
//  phase3: y^T = W1^T att^T (16x16x32_f16) -> float4 stores.
// LDS: vth 9216 + qh 8192 + kh 8192 = 25600 B -> 6 blocks/CU.

typedef __attribute__((ext_vector_type(8))) __fp16 half8;
typedef __attribute__((ext_vector_type(4))) __fp16 half4;
typedef __attribute__((ext_vector_type(2))) __fp16 half2v;
typedef __attribute__((ext_vector_type(4))) float f32x4;

__global__ void prep_weights(const float* __restrict__ Wq,
                             const float* __restrict__ Wk,
                             const float* __restrict__ Wv,
                             const float* __restrict__ W1,
                             __fp16* __restrict__ ws)
{
    int i = blockIdx.x * 256 + threadIdx.x;      // 16384 total
    if (i < 12288) {
        int n = i >> 6, c = i & 63;
        int sec = n >> 6;
        const float* src = (sec == 0) ? Wq : (sec == 1) ? Wk : Wv;
        int h = (n & 63) >> 3, d = n & 7;
        float v = src[h * 512 + c * 8 + d];
        if (sec == 1) v *= 0.18033688011112042f;   // C^-0.5 * log2(e) into K
        ws[i] = (__fp16)v;
    } else {
        int j = (i - 12288) >> 6, c = i & 63;
        ws[i] = (__fp16)W1[c * 64 + j];
    }
}

__device__ __forceinline__ uint32_t pk2h(float a, float b) {
    half2v h = __builtin_amdgcn_cvt_pkrtz(a, b);
    union { half2v h; uint32_t u; } c;
    c.h = h;
    return c.u;
}

__global__ __launch_bounds__(256, 6) void mha_mfma4_kernel(
    const float* __restrict__ x,
    const __fp16* __restrict__ wT,
    const float* __restrict__ b1v,
    float* __restrict__ y)
{
    __shared__ __align__(16) __fp16 vth[64 * 72];     // V^T[h][d][s]
    __shared__ __align__(16) __fp16 qh[8 * 64 * 8];   // Q[h][t][d] -> att
    __shared__ __align__(16) __fp16 kh[8 * 64 * 8];   // K[h][s][d]

    const int b    = blockIdx.x;
    const int tid  = threadIdx.x;
    const int lane = tid & 63;
    const int w    = tid >> 6;
    const int l15  = lane & 15;
    const int quad = lane >> 4;

    // ---------------- phase 1: QKV^T = Wqkv^T x^T ----------------
    {
        // x B-frags straight from global (no LDS staging): lane needs
        // x[16tt+l15][32ks+8quad .. +7] as fp16 — same values phase 0
        // used to stage. All 4 waves read the same 16KB -> L1-served.
        half8 xfr[4][2];
        const float* xb = x + (size_t)b * 4096;
        #pragma unroll
        for (int tt = 0; tt < 4; ++tt)
            #pragma unroll
            for (int ks = 0; ks < 2; ++ks) {
                const float* xp = xb + (16 * tt + l15) * 64 + 32 * ks + 8 * quad;
                float4 g0 = ((const float4*)xp)[0];
                float4 g1 = ((const float4*)xp)[1];
                union { half2v h2[4]; half8 h8; } u;
                u.h2[0] = __builtin_amdgcn_cvt_pkrtz(g0.x, g0.y);
                u.h2[1] = __builtin_amdgcn_cvt_pkrtz(g0.z, g0.w);
                u.h2[2] = __builtin_amdgcn_cvt_pkrtz(g1.x, g1.y);
                u.h2[3] = __builtin_amdgcn_cvt_pkrtz(g1.z, g1.w);
                xfr[tt][ks] = u.h8;
            }

        #pragma unroll
        for (int i = 0; i < 3; ++i) {
            int mt = 3 * w + i;                       // m-tile over n=0..191
            const __fp16* ap = wT + (16 * mt + l15) * 64 + 8 * quad;
            half8 a0 = *(const half8*)ap;
            half8 a1 = *(const half8*)(ap + 32);
            #pragma unroll
            for (int tt = 0; tt < 4; ++tt) {
                f32x4 acc = {0.f, 0.f, 0.f, 0.f};
                acc = __builtin_amdgcn_mfma_f32_16x16x32_f16(a0, xfr[tt][0], acc, 0, 0, 0);
                acc = __builtin_amdgcn_mfma_f32_16x16x32_f16(a1, xfr[tt][1], acc, 0, 0, 0);
                // thread holds n = 16mt+4quad+r, t = 16tt+l15
                int t = 16 * tt + l15;
                union { uint32_t u2[2]; uint2 u; } pq;
                pq.u2[0] = pk2h(acc[0], acc[1]);
                pq.u2[1] = pk2h(acc[2], acc[3]);
                if (mt < 4) {
                    int hq = 2 * mt + (quad >> 1);
                    *(uint2*)&qh[(hq * 64 + t) * 8 + 4 * (quad & 1)] = pq.u;
                } else if (mt < 8) {
                    int hk = 2 * (mt - 4) + (quad >> 1);
                    *(uint2*)&kh[(hk * 64 + t) * 8 + 4 * (quad & 1)] = pq.u;
                } else {
                    int hv = 2 * (mt - 8) + (quad >> 1);
                    int d0 = 4 * (quad & 1);
                    #pragma unroll
                    for (int r = 0; r < 4; ++r)
                        vth[(hv * 8 + d0 + r) * 72 + t] = (__fp16)acc[r];
                }
            }
        }
    }
    __syncthreads();

    const half4 z4 = {};
    const bool dv = (quad < 2);                      // quads holding valid d (0..7)
    // causal mask predicate per r (lane-constant, hoisted out of the loops)
    bool mrk[4];
    #pragma unroll
    for (int r = 0; r < 4; ++r) mrk[r] = (4 * quad + r) > l15;

    // ---------------- phase 2: attention, heads h = 2w, 2w+1 ----------------
    // 16x16x16_f16: A[m][k]: m=l15, k=4*quad+j.  B[k][n]: n=l15, k=4*quad+j.
    // D[row][col]: row=4*quad+r, col=l15.  S^T output layout == PV B-frag layout.
    #pragma unroll 1
    for (int hh = 0; hh < 2; ++hh) {
        const int h = 2 * w + hh;
        half4 kfr[4], vfr[4];
        #pragma unroll
        for (int tm = 0; tm < 4; ++tm)   // A-frag of K: m=s row, k=d=4q+j (q<2)
            kfr[tm] = dv ? *(const half4*)&kh[(h * 64 + 16 * tm + l15) * 8 + 4 * quad] : z4;
        #pragma unroll
        for (int km = 0; km < 4; ++km)   // A-frag of V^T: m=d=l15 (<8), k=s=16km+4q+j
            vfr[km] = (l15 < 8) ? *(const half4*)&vth[(h * 8 + l15) * 72 + 16 * km + 4 * quad] : z4;

        #pragma unroll
        for (int tn = 0; tn < 4; ++tn) {
            half4 qf = dv ? *(const half4*)&qh[(h * 64 + 16 * tn + l15) * 8 + 4 * quad] : z4;

            f32x4 S[4];   // S^T tiles in column tn, tm <= tn
            #pragma unroll
            for (int tm = 0; tm <= tn; ++tm) {
                f32x4 zz = {0.f, 0.f, 0.f, 0.f};
                S[tm] = __builtin_amdgcn_mfma_f32_16x16x16f16(kfr[tm], qf, zz, 0, 0, 0);
            }

            // max-free softmax (scores bounded); scale pre-folded into K.
            // Tree-reassociated denominator: pairwise within a tile, two
            // alternating cross-tile accumulators (depth ~5 vs serial 16).
            float acc0 = 0.f, acc1 = 0.f;
            #pragma unroll
            for (int tm = 0; tm <= tn; ++tm) {
                float e0 = __builtin_exp2f(S[tm][0]);
                float e1 = __builtin_exp2f(S[tm][1]);
                float e2 = __builtin_exp2f(S[tm][2]);
                float e3 = __builtin_exp2f(S[tm][3]);
                if (tm == tn) {             // causal mask on the diagonal tile
                    if (mrk[0]) e0 = 0.f;
                    if (mrk[1]) e1 = 0.f;
                    if (mrk[2]) e2 = 0.f;
                    if (mrk[3]) e3 = 0.f;
                }
                S[tm][0] = e0; S[tm][1] = e1; S[tm][2] = e2; S[tm][3] = e3;
                float ts = (e0 + e1) + (e2 + e3);
                if (tm & 1) acc1 += ts; else acc0 += ts;
            }
            float ls = acc0 + acc1;
            ls += __shfl_xor(ls, 16);
            ls += __shfl_xor(ls, 32);
            float inv = __builtin_amdgcn_rcpf(ls);

            // O^T col tn: packed P IS the B-frag (k=4q+j == s layout). No shuffle.
            f32x4 O = {0.f, 0.f, 0.f, 0.f};
            #pragma unroll
            for (int km = 0; km <= tn; ++km) {
                union { uint32_t u[2]; half4 h4; } bu;
                bu.u[0] = pk2h(S[km][0], S[km][1]);
                bu.u[1] = pk2h(S[km][2], S[km][3]);
                O = __builtin_amdgcn_mfma_f32_16x16x16f16(vfr[km], bu.h4, O, 0, 0, 0);
            }

            // O^T: row d=4q+r (valid for q<2), col t=16tn+l15; normalize by own column sum
            if (dv) {
                union { uint32_t u2[2]; uint2 u; } po;
                po.u2[0] = pk2h(O[0] * inv, O[1] * inv);
                po.u2[1] = pk2h(O[2] * inv, O[3] * inv);
                *(uint2*)&qh[(h * 64 + 16 * tn + l15) * 8 + 4 * quad] = po.u;
            }
        }
    }
    __syncthreads();

    // ---------------- phase 3: y^T = W1^T att^T ----------------
    {
        const __fp16* wp = wT + 12288 + (16 * w + l15) * 64 + 8 * quad;
        half8 w0 = *(const half8*)wp;
        half8 w1 = *(const half8*)(wp + 32);
        float4 bias4 = *(const float4*)&b1v[16 * w + 4 * quad];
        float* yb = y + (size_t)b * 4096;
        #pragma unroll
        for (int tt = 0; tt < 4; ++tt) {
            half8 bq0 = *(const half8*)&qh[(quad * 64 + 16 * tt + l15) * 8];       // k: h=quad
            half8 bq1 = *(const half8*)&qh[((4 + quad) * 64 + 16 * tt + l15) * 8]; // k: h=4+quad
            f32x4 acc = {0.f, 0.f, 0.f, 0.f};
            acc = __builtin_amdgcn_mfma_f32_16x16x32_f16(w0, bq0, acc, 0, 0, 0);
            acc = __builtin_amdgcn_mfma_f32_16x16x32_f16(w1, bq1, acc, 0, 0, 0);
            float4 o;
            o.x = fmaxf(acc[0] + bias4.x, 0.f);
            o.y = fmaxf(acc[1] + bias4.y, 0.f);
            o.z = fmaxf(acc[2] + bias4.z, 0.f);
            o.w = fmaxf(acc[3] + bias4.w, 0.f);
            *(float4*)&yb[(16 * tt + l15) * 64 + 16 * w + 4 * quad] = o;
        }
    }
}

extern "C" void kernel_launch(void* const* d_in, const int* in_sizes, int n_in,
                              void* d_out, int out_size, void* d_ws, size_t ws_size,
                              hipStream_t stream) {
    const float* x  = (const float*)d_in[0];
    const float* Wq = (const float*)d_in[1];
    const float* Wk = (const float*)d_in[2];
    const float* Wv = (const float*)d_in[3];
    const float* W1 = (const float*)d_in[4];
    const float* b1 = (const float*)d_in[5];
    float* y = (float*)d_out;
    __fp16* ws = (__fp16*)d_ws;

    const int B = in_sizes[0] / 4096;   // 4096
    prep_weights<<<64, 256, 0, stream>>>(Wq, Wk, Wv, W1, ws);
    mha_mfma4_kernel<<<B, 256, 0, stream>>>(x, ws, b1, y);
}

// Round 13
// 139.536 us; speedup vs baseline: 1.2520x; 1.2520x over previous
//
#include <hip/hip_runtime.h>
#include <math.h>

// B=4096, T=64, C=64, H=8, D=8. fp32 in/out.
// d_ws fp16: WqkvT[n][c] (n: q 0-63 | k 64-127 | v 128-191), then W1T[j][c].
// Wk section PRE-SCALED by C^-0.5*log2(e) so softmax is exp2(S) directly.
// Main kernel: 256 thr (4 waves) per batch element, 6 blocks/CU (LDS 25600B).
// FINAL = R9 structure (measured optimum, 49.6us) + tree-reassociated
// softmax denominator (the only liveness-neutral piece of R10; R10's raw
// de-predicated qf/vfr loads are EXCLUDED - they added 0.5M bank conflicts).
// Session rules (measured R3-R11): (a) any register-liveness extension
// across a phase boundary spills (K/Q-in-regs, head braid, mask-in-C,
// MFMA-denominator, global x-frags: all +20..49MB HBM, +10..35us);
// (b) 8 blocks/CU thrashes per-XCD L2 (write amplification 1.7-2x);
// (c) only in-place, liveness-neutral VALU cuts win (scale fold: -1.5us).
//  phase0: x -> fp16 LDS xs[64][72]       (region0)
//  phase1: QKV^T = Wqkv^T x^T via 16x16x32_f16 (A=weights, B=x frags cached
//          in regs). Packed C -> qh (Q), kh (K); V scalar -> vth (region0
//          overlay, after the xs-consumed barrier). Barrier (cross-wave).
//  phase2: per wave, heads 2w,2w+1 with 16x16x16_f16 (K=16): A/B frags hold
//          k=4*quad+j == the S^T C-layout, so packed softmax output IS the
//          PV B-operand (no shuffle). S^T col tn: tm<=tn triangular MFMAs;
//          max-free softmax e=exp2(s) (scale pre-folded), causal cndmask on
//          diagonal, tree row-sum + shfl_xor(16,32); O^T = V^T P;
//          normalize by rcp; att -> qh.
//  phase3: y^T = W1^T att^T (16x16x32_f16) -> float4 stores.
// LDS: region0 9216 (xs|vth) + qh 8192 + kh 8192 = 25600 B -> 6 blocks/CU.

typedef __attribute__((ext_vector_type(8))) __fp16 half8;
typedef __attribute__((ext_vector_type(4))) __fp16 half4;
typedef __attribute__((ext_vector_type(2))) __fp16 half2v;
typedef __attribute__((ext_vector_type(4))) float f32x4;

__global__ void prep_weights(const float* __restrict__ Wq,
                             const float* __restrict__ Wk,
                             const float* __restrict__ Wv,
                             const float* __restrict__ W1,
                             __fp16* __restrict__ ws)
{
    int i = blockIdx.x * 256 + threadIdx.x;      // 16384 total
    if (i < 12288) {
        int n = i >> 6, c = i & 63;
        int sec = n >> 6;
        const float* src = (sec == 0) ? Wq : (sec == 1) ? Wk : Wv;
        int h = (n & 63) >> 3, d = n & 7;
        float v = src[h * 512 + c * 8 + d];
        if (sec == 1) v *= 0.18033688011112042f;   // C^-0.5 * log2(e) into K
        ws[i] = (__fp16)v;
    } else {
        int j = (i - 12288) >> 6, c = i & 63;
        ws[i] = (__fp16)W1[c * 64 + j];
    }
}

__device__ __forceinline__ uint32_t pk2h(float a, float b) {
    half2v h = __builtin_amdgcn_cvt_pkrtz(a, b);
    union { half2v h; uint32_t u; } c;
    c.h = h;
    return c.u;
}

__global__ __launch_bounds__(256, 6) void mha_mfma4_kernel(
    const float* __restrict__ x,
    const __fp16* __restrict__ wT,
    const float* __restrict__ b1v,
    float* __restrict__ y)
{
    __shared__ __align__(16) __fp16 region0[64 * 72]; // xs, later vth
    __shared__ __align__(16) __fp16 qh[8 * 64 * 8];   // Q[h][t][d] -> att
    __shared__ __align__(16) __fp16 kh[8 * 64 * 8];   // K[h][s][d]

    __fp16* xs  = region0;            // [64][72]
    __fp16* vth = region0;            // V^T[h][d][s], [64][72] overlay

    const int b    = blockIdx.x;
    const int tid  = threadIdx.x;
    const int lane = tid & 63;
    const int w    = tid >> 6;
    const int l15  = lane & 15;
    const int quad = lane >> 4;

    // ---------------- phase 0: stage x -> fp16 ----------------
    {
        int r = tid >> 2, c0 = (tid & 3) * 16;
        const float* xp = x + (size_t)b * 4096 + r * 64 + c0;
        float4 f0 = ((const float4*)xp)[0];
        float4 f1 = ((const float4*)xp)[1];
        float4 f2 = ((const float4*)xp)[2];
        float4 f3 = ((const float4*)xp)[3];
        union { half2v h2[4]; float4 f; } u0, u1;
        u0.h2[0] = __builtin_amdgcn_cvt_pkrtz(f0.x, f0.y);
        u0.h2[1] = __builtin_amdgcn_cvt_pkrtz(f0.z, f0.w);
        u0.h2[2] = __builtin_amdgcn_cvt_pkrtz(f1.x, f1.y);
        u0.h2[3] = __builtin_amdgcn_cvt_pkrtz(f1.z, f1.w);
        u1.h2[0] = __builtin_amdgcn_cvt_pkrtz(f2.x, f2.y);
        u1.h2[1] = __builtin_amdgcn_cvt_pkrtz(f2.z, f2.w);
        u1.h2[2] = __builtin_amdgcn_cvt_pkrtz(f3.x, f3.y);
        u1.h2[3] = __builtin_amdgcn_cvt_pkrtz(f3.z, f3.w);
        *(float4*)&xs[r * 72 + c0]     = u0.f;
        *(float4*)&xs[r * 72 + c0 + 8] = u1.f;
    }
    __syncthreads();

    // ---------------- phase 1: QKV^T = Wqkv^T x^T ----------------
    {
        half8 xfr[4][2];   // B-frags (x)
        #pragma unroll
        for (int tt = 0; tt < 4; ++tt)
            #pragma unroll
            for (int ks = 0; ks < 2; ++ks)
                xfr[tt][ks] = *(const half8*)&xs[(16 * tt + l15) * 72 + 32 * ks + 8 * quad];
        __syncthreads();    // xs fully consumed; region0 now writable as vth

        #pragma unroll
        for (int i = 0; i < 3; ++i) {
            int mt = 3 * w + i;                       // m-tile over n=0..191
            const __fp16* ap = wT + (16 * mt + l15) * 64 + 8 * quad;
            half8 a0 = *(const half8*)ap;
            half8 a1 = *(const half8*)(ap + 32);
            #pragma unroll
            for (int tt = 0; tt < 4; ++tt) {
                f32x4 acc = {0.f, 0.f, 0.f, 0.f};
                acc = __builtin_amdgcn_mfma_f32_16x16x32_f16(a0, xfr[tt][0], acc, 0, 0, 0);
                acc = __builtin_amdgcn_mfma_f32_16x16x32_f16(a1, xfr[tt][1], acc, 0, 0, 0);
                // thread holds n = 16mt+4quad+r, t = 16tt+l15
                int t = 16 * tt + l15;
                union { uint32_t u2[2]; uint2 u; } pq;
                pq.u2[0] = pk2h(acc[0], acc[1]);
                pq.u2[1] = pk2h(acc[2], acc[3]);
                if (mt < 4) {
                    int hq = 2 * mt + (quad >> 1);
                    *(uint2*)&qh[(hq * 64 + t) * 8 + 4 * (quad & 1)] = pq.u;
                } else if (mt < 8) {
                    int hk = 2 * (mt - 4) + (quad >> 1);
                    *(uint2*)&kh[(hk * 64 + t) * 8 + 4 * (quad & 1)] = pq.u;
                } else {
                    int hv = 2 * (mt - 8) + (quad >> 1);
                    int d0 = 4 * (quad & 1);
                    #pragma unroll
                    for (int r = 0; r < 4; ++r)
                        vth[(hv * 8 + d0 + r) * 72 + t] = (__fp16)acc[r];
                }
            }
        }
    }
    __syncthreads();

    const half4 z4 = {};
    const bool dv = (quad < 2);                      // quads holding valid d (0..7)
    // causal mask predicate per r (lane-constant, hoisted out of the loops)
    bool mrk[4];
    #pragma unroll
    for (int r = 0; r < 4; ++r) mrk[r] = (4 * quad + r) > l15;

    // ---------------- phase 2: attention, heads h = 2w, 2w+1 ----------------
    // 16x16x16_f16: A[m][k]: m=l15, k=4*quad+j.  B[k][n]: n=l15, k=4*quad+j.
    // D[row][col]: row=4*quad+r, col=l15.  S^T output layout == PV B-frag layout.
    #pragma unroll 1
    for (int hh = 0; hh < 2; ++hh) {
        const int h = 2 * w + hh;
        half4 kfr[4], vfr[4];
        #pragma unroll
        for (int tm = 0; tm < 4; ++tm)   // A-frag of K: m=s row, k=d=4q+j (q<2)
            kfr[tm] = dv ? *(const half4*)&kh[(h * 64 + 16 * tm + l15) * 8 + 4 * quad] : z4;
        #pragma unroll
        for (int km = 0; km < 4; ++km)   // A-frag of V^T: m=d=l15 (<8), k=s=16km+4q+j
            vfr[km] = (l15 < 8) ? *(const half4*)&vth[(h * 8 + l15) * 72 + 16 * km + 4 * quad] : z4;

        #pragma unroll
        for (int tn = 0; tn < 4; ++tn) {
            half4 qf = dv ? *(const half4*)&qh[(h * 64 + 16 * tn + l15) * 8 + 4 * quad] : z4;

            f32x4 S[4];   // S^T tiles in column tn, tm <= tn
            #pragma unroll
            for (int tm = 0; tm <= tn; ++tm) {
                f32x4 zz = {0.f, 0.f, 0.f, 0.f};
                S[tm] = __builtin_amdgcn_mfma_f32_16x16x16f16(kfr[tm], qf, zz, 0, 0, 0);
            }

            // max-free softmax (scores bounded); scale pre-folded into K.
            // Tree-reassociated denominator: pairwise within a tile, two
            // alternating cross-tile accumulators (depth ~5 vs serial 16).
            float acc0 = 0.f, acc1 = 0.f;
            #pragma unroll
            for (int tm = 0; tm <= tn; ++tm) {
                float e0 = __builtin_exp2f(S[tm][0]);
                float e1 = __builtin_exp2f(S[tm][1]);
                float e2 = __builtin_exp2f(S[tm][2]);
                float e3 = __builtin_exp2f(S[tm][3]);
                if (tm == tn) {             // causal mask on the diagonal tile
                    if (mrk[0]) e0 = 0.f;
                    if (mrk[1]) e1 = 0.f;
                    if (mrk[2]) e2 = 0.f;
                    if (mrk[3]) e3 = 0.f;
                }
                S[tm][0] = e0; S[tm][1] = e1; S[tm][2] = e2; S[tm][3] = e3;
                float ts = (e0 + e1) + (e2 + e3);
                if (tm & 1) acc1 += ts; else acc0 += ts;
            }
            float ls = acc0 + acc1;
            ls += __shfl_xor(ls, 16);
            ls += __shfl_xor(ls, 32);
            float inv = __builtin_amdgcn_rcpf(ls);

            // O^T col tn: packed P IS the B-frag (k=4q+j == s layout). No shuffle.
            f32x4 O = {0.f, 0.f, 0.f, 0.f};
            #pragma unroll
            for (int km = 0; km <= tn; ++km) {
                union { uint32_t u[2]; half4 h4; } bu;
                bu.u[0] = pk2h(S[km][0], S[km][1]);
                bu.u[1] = pk2h(S[km][2], S[km][3]);
                O = __builtin_amdgcn_mfma_f32_16x16x16f16(vfr[km], bu.h4, O, 0, 0, 0);
            }

            // O^T: row d=4q+r (valid for q<2), col t=16tn+l15; normalize by own column sum
            if (dv) {
                union { uint32_t u2[2]; uint2 u; } po;
                po.u2[0] = pk2h(O[0] * inv, O[1] * inv);
                po.u2[1] = pk2h(O[2] * inv, O[3] * inv);
                *(uint2*)&qh[(h * 64 + 16 * tn + l15) * 8 + 4 * quad] = po.u;
            }
        }
    }
    __syncthreads();

    // ---------------- phase 3: y^T = W1^T att^T ----------------
    {
        const __fp16* wp = wT + 12288 + (16 * w + l15) * 64 + 8 * quad;
        half8 w0 = *(const half8*)wp;
        half8 w1 = *(const half8*)(wp + 32);
        float4 bias4 = *(const float4*)&b1v[16 * w + 4 * quad];
        float* yb = y + (size_t)b * 4096;
        #pragma unroll
        for (int tt = 0; tt < 4; ++tt) {
            half8 bq0 = *(const half8*)&qh[(quad * 64 + 16 * tt + l15) * 8];       // k: h=quad
            half8 bq1 = *(const half8*)&qh[((4 + quad) * 64 + 16 * tt + l15) * 8]; // k: h=4+quad
            f32x4 acc = {0.f, 0.f, 0.f, 0.f};
            acc = __builtin_amdgcn_mfma_f32_16x16x32_f16(w0, bq0, acc, 0, 0, 0);
            acc = __builtin_amdgcn_mfma_f32_16x16x32_f16(w1, bq1, acc, 0, 0, 0);
            float4 o;
            o.x = fmaxf(acc[0] + bias4.x, 0.f);
            o.y = fmaxf(acc[1] + bias4.y, 0.f);
            o.z = fmaxf(acc[2] + bias4.z, 0.f);
            o.w = fmaxf(acc[3] + bias4.w, 0.f);
            *(float4*)&yb[(16 * tt + l15) * 64 + 16 * w + 4 * quad] = o;
        }
    }
}

extern "C" void kernel_launch(void* const* d_in, const int* in_sizes, int n_in,
                              void* d_out, int out_size, void* d_ws, size_t ws_size,
                              hipStream_t stream) {
    const float* x  = (const float*)d_in[0];
    const float* Wq = (const float*)d_in[1];
    const float* Wk = (const float*)d_in[2];
    const float* Wv = (const float*)d_in[3];
    const float* W1 = (const float*)d_in[4];
    const float* b1 = (const float*)d_in[5];
    float* y = (float*)d_out;
    __fp16* ws = (__fp16*)d_ws;

    const int B = in_sizes[0] / 4096;   // 4096
    prep_weights<<<64, 256, 0, stream>>>(Wq, Wk, Wv, W1, ws);
    mha_mfma4_kernel<<<B, 256, 0, stream>>>(x, ws, b1, y);
}